// Round 8
// baseline (148.471 us; speedup 1.0000x reference)
//
#include <hip/hip_runtime.h>
#include <hip/hip_bf16.h>

typedef __bf16 bf16;
typedef __attribute__((ext_vector_type(8))) __bf16 bf16x8;
typedef __attribute__((ext_vector_type(4))) __bf16 bf16x4;
typedef __attribute__((ext_vector_type(16))) float f32x16;

#define N_ROWS 16384
#define DIM 256
#define NJC 512           /* 32-col tiles */
#define NBLKS 768         /* 3 blocks/CU x 256 CU = exact residency */
#define TPB 43            /* 33024 / 768 exactly */
#define NTILES 33024      /* sum_{it=0}^{127} (512-4it) */
#define SQK1 4.53981608f  /* sqrt(1/(0.07*ln2)): A pre-scaled so e^{z} = 2^{dot'} */
#define LN2F 0.69314718056f

#define WS_T_OFF (N_ROWS * DIM * 2)
#define WS_D_OFF (WS_T_OFF + N_ROWS * 4)

#define GLOAD_LDS(g, l)                                        \
    __builtin_amdgcn_global_load_lds(                          \
        (const __attribute__((address_space(1))) void*)(g),    \
        (__attribute__((address_space(3))) void*)(l), 16, 0, 0)

// Kernel 1: L2-normalize rows, scale by SQK1, emit bf16 A' to ws. Zeros T[]
// and d_out. Dg[row] = s2' = sum(bf16(SQK1*a)^2) = the MFMA diagonal, so the
// diagonal's bf16 rounding error cancels: loss_i = ln2*(log2(T'_i) - s2'_i).
__global__ void __launch_bounds__(256) normalize_kernel(const float* __restrict__ in,
                                                        bf16* __restrict__ out,
                                                        float* __restrict__ Tg,
                                                        float* __restrict__ Dg,
                                                        float* __restrict__ loss_out) {
    if (blockIdx.x == 0 && threadIdx.x == 0) loss_out[0] = 0.0f;
    if (blockIdx.x < 64) Tg[blockIdx.x * 256 + threadIdx.x] = 0.0f;

    const int row  = blockIdx.x * 4 + (threadIdx.x >> 6);
    const int lane = threadIdx.x & 63;
    const float4* rp = (const float4*)(in + (size_t)row * DIM);
    float4 v = rp[lane];
    float ss = v.x * v.x + v.y * v.y + v.z * v.z + v.w * v.w;
#pragma unroll
    for (int m = 1; m < 64; m <<= 1) ss += __shfl_xor(ss, m, 64);
    float inv = SQK1 / fmaxf(sqrtf(ss), 1e-12f);
    bf16x4 o;
    o[0] = (bf16)(v.x * inv);
    o[1] = (bf16)(v.y * inv);
    o[2] = (bf16)(v.z * inv);
    o[3] = (bf16)(v.w * inv);
    *(bf16x4*)(out + (size_t)row * DIM + lane * 4) = o;

    float f0 = (float)o[0], f1 = (float)o[1], f2 = (float)o[2], f3 = (float)o[3];
    float s2 = f0 * f0 + f1 * f1 + f2 * f2 + f3 * f3;
#pragma unroll
    for (int m = 1; m < 64; m <<= 1) s2 += __shfl_xor(s2, m, 64);
    if (lane == 0) Dg[row] = s2;
}

// Tree-reduce 16 floats across the 32 `lo` lanes; every lane ends with the
// full sum for register index r = (lo>>1)&15. (Correctness-proven R4-R10.)
#define TREE16(R, out)                                                     \
    do {                                                                   \
        float w8[8], w4[4], w2[2], w1, g_;                                 \
        _Pragma("unroll") for (int i_ = 0; i_ < 8; ++i_) {                 \
            g_ = (lo & 16) ? R[i_] : R[i_ + 8];                            \
            w8[i_] = ((lo & 16) ? R[i_ + 8] : R[i_]) + __shfl_xor(g_, 16); \
        }                                                                  \
        _Pragma("unroll") for (int i_ = 0; i_ < 4; ++i_) {                 \
            g_ = (lo & 8) ? w8[i_] : w8[i_ + 4];                           \
            w4[i_] = ((lo & 8) ? w8[i_ + 4] : w8[i_]) + __shfl_xor(g_, 8); \
        }                                                                  \
        _Pragma("unroll") for (int i_ = 0; i_ < 2; ++i_) {                 \
            g_ = (lo & 4) ? w4[i_] : w4[i_ + 2];                           \
            w2[i_] = ((lo & 4) ? w4[i_ + 2] : w4[i_]) + __shfl_xor(g_, 4); \
        }                                                                  \
        g_ = (lo & 2) ? w2[0] : w2[1];                                     \
        w1 = ((lo & 2) ? w2[1] : w2[0]) + __shfl_xor(g_, 2);               \
        out = w1 + __shfl_xor(w1, 1);                                      \
    } while (0)

// Kernel 2: symmetric A'A'^T + softmax denominator.
// R17 -> R18 (data path & per-tile work untouched; LDS=73%-busy governor,
// sync exposure is the 27% slack):
// (a) TRIPLE-BUFFER, SINGLE BARRIER, PRE-BARRIER VMCNT. 3x16KB buffers
//     (48KB/block, 3 blocks = 144KB <= 160). Iter t: [wait own L_t
//     (vmcnt(5) steady: leaves A(t-1)+L(t+1) in flight) -> s_barrier ->
//     ISSUE tile t+2 into buf((t+2)%3) -> kloop -> epilogue]. The wait sits
//     BEFORE the barrier where L_t already has ~2 tile-times of hiding;
//     one barrier per tile instead of two. Overwrite-safety: ISSUE target
//     = tile (t-1)'s buffer, whose readers all passed this iter's barrier.
//     Visibility: every wave drains its own loads pre-barrier.
// (b) XCD-CHUNKED SWIZZLE (768%8==0, bijective): work id = (bid%8)*96 +
//     bid/8 -> consecutive tile ranges share an XCD's L2; each strip's
//     sequential B-stream fetched ~once per XCD instead of 8x.
__global__ void __launch_bounds__(256, 3)
loss_kernel(const bf16* __restrict__ A, float* __restrict__ Tg) {
    __shared__ bf16 Bs[3][32 * DIM];        // 48 KB

    const int tid = threadIdx.x;
    const int w  = tid >> 6;      // wave = row-group: rows w*32..+31 of the 128-row strip
    const int l  = tid & 63;
    const int lo = l & 31, hi = l >> 5;

    // XCD-chunked bijective swizzle: blocks dispatched round-robin over 8
    // XCDs; give XCD x the contiguous work range [x*96, (x+1)*96).
    const int bid = (int)(blockIdx.x & 7) * (NBLKS / 8) + (int)(blockIdx.x >> 3);
    const int tbeg = bid * TPB;

    // decode starting (it, jc): C(it) = 2*it*(257-it) <= tbeg < C(it+1)
    int it = 0;
    while (2 * (it + 1) * (257 - (it + 1)) <= tbeg) ++it;
    int jc = 4 * it + (tbeg - 2 * it * (257 - it));

    // lookahead tile indices (t+1, t+2)
#define ADV(ITX, JCX)                                                        \
    do { if (++JCX == NJC) { ++ITX; JCX = 4 * ITX; } } while (0)
    int it1 = it, jc1 = jc; ADV(it1, jc1);
    int it2 = it1, jc2 = jc1; ADV(it2, jc2);

    // persistent A fragments for the wave's 32 rows (A-op: m=lo, k=hi*8+j)
    bf16x8 af[16];
#define LOAD_AF(ITX)                                                         \
    do {                                                                     \
        const bf16* ap_ = A + (size_t)((ITX) * 128 + w * 32 + lo) * DIM + hi * 8; \
        _Pragma("unroll") for (int k_ = 0; k_ < 16; ++k_)                    \
            af[k_] = *(const bf16x8*)(ap_ + k_ * 16);                        \
    } while (0)
    LOAD_AF(it);

    float s0[16];
#pragma unroll
    for (int r = 0; r < 16; ++r) s0[r] = 0.f;

    // DMA lane constants. Wave w stages B-tile rows w*8..+7 in 4 instrs
    // (2 rows each). Lane: rl = l>>5 (row in pair), s = l&31 (LDS slot).
    // Slot s of row r holds global chunk c = (s&24)|((s&7)^(r&7)).
    const int s_dma = l & 31;
    const int rl    = l >> 5;
    int vo[4];
#pragma unroll
    for (int q = 0; q < 4; ++q) {
        const int c = (s_dma & 24) | ((s_dma & 7) ^ ((q * 2 + rl) & 7));
        vo[q] = rl * DIM + c * 8;
    }

    // fragment-read constants: B row = lo; chunk cc at slot (cc&24)|((cc&7)^(lo&7))
    const int rbase = lo * DIM;
    const int mx7 = lo & 7;

#define ISSUE(jcn_, BUF)                                                     \
    do {                                                                     \
        const bf16* tb_ = A + (size_t)((jcn_) * 32 + w * 8) * DIM;           \
        bf16* lb_ = (BUF) + (w * 8) * DIM;                                   \
        _Pragma("unroll") for (int q_ = 0; q_ < 4; ++q_) {                   \
            GLOAD_LDS(tb_ + (q_ * 2) * DIM + vo[q_],                         \
                      lb_ + (q_ * 2) * DIM);                                 \
        }                                                                    \
    } while (0)

#define FLUSH_ROWS                                                           \
    do {                                                                     \
        float tr_;                                                           \
        TREE16(s0, tr_);                                                     \
        const int r_ = (lo >> 1) & 15;                                       \
        const int rowoff_ = (r_ & 3) + 8 * (r_ >> 2) + 4 * hi;               \
        if ((l & 1) == 0)                                                    \
            atomicAdd(&Tg[it * 128 + w * 32 + rowoff_], tr_);                \
    } while (0)

    int t = 0;

    // BODY: process tile (it,jc) reading BR; prefetch tile (it2,jc2) into BW.
    // WN0: vmcnt immediate when a prefetch exists; WL: when not.
#define BODY(BR, BW, WN0, WL)                                                \
    do {                                                                     \
        if (t + 2 < TPB) {                                                   \
            asm volatile("s_waitcnt vmcnt(" #WN0 ")" ::: "memory");          \
        } else {                                                             \
            asm volatile("s_waitcnt vmcnt(" #WL ")" ::: "memory");           \
        }                                                                    \
        asm volatile("s_barrier" ::: "memory");                              \
        if (t + 2 < TPB) ISSUE(jc2, BW);                                     \
        f32x16 c0;                                                           \
        _Pragma("unroll") for (int r_ = 0; r_ < 16; ++r_) c0[r_] = 0.f;      \
        __builtin_amdgcn_s_setprio(1);                                       \
        _Pragma("unroll") for (int k_ = 0; k_ < 16; ++k_) {                  \
            const int cc_ = k_ * 2 + hi;                                     \
            const int slot_ = (cc_ & 24) | ((cc_ & 7) ^ mx7);                \
            bf16x8 b_ = *(const bf16x8*)&(BR)[rbase + slot_ * 8];            \
            c0 = __builtin_amdgcn_mfma_f32_32x32x16_bf16(af[k_], b_, c0, 0, 0, 0); \
        }                                                                    \
        __builtin_amdgcn_s_setprio(0);                                       \
        float cs_ = 0.f;                                                     \
        _Pragma("unroll") for (int r_ = 0; r_ < 16; ++r_) {                  \
            float e_ = __builtin_amdgcn_exp2f(c0[r_]);                       \
            s0[r_] += e_;                                                    \
            cs_ += e_;                                                       \
        }                                                                    \
        cs_ += __shfl_xor(cs_, 32);                                          \
        /* col-sum flush: UNCONDITIONAL instr (uniform vmcnt queue); adds  */ \
        /* 0.0 on the diagonal 128x128 block (covered by row sums).        */ \
        const float fv_ = ((jc >> 2) == it) ? 0.0f : cs_;                    \
        if (hi == 0) atomicAdd(&Tg[jc * 32 + lo], fv_);                      \
        if (t + 1 < TPB) {                                                   \
            if (it1 != it) {                                                 \
                FLUSH_ROWS;                                                  \
                LOAD_AF(it1);                                                \
                _Pragma("unroll") for (int r_ = 0; r_ < 16; ++r_) s0[r_] = 0.f; \
            }                                                                \
            it = it1; jc = jc1; it1 = it2; jc1 = jc2; ADV(it2, jc2);         \
        }                                                                    \
        ++t;                                                                 \
    } while (0)

    // prologue: stage tiles 0 and 1 (TPB=43 >= 2, unconditional)
    ISSUE(jc, &Bs[0][0]);
    ISSUE(jc1, &Bs[1][0]);

    // t=0 peeled: queue [L0(4), L1(4)] -> vmcnt(4) retires L0 (no atomic yet)
    BODY(&Bs[0][0], &Bs[2][0], 4, 0);
    // steady: queue [L_t(4), A(t-1), L_{t+1}(4)] -> vmcnt(5); tail -> 1
    while (t < TPB) {
        BODY(&Bs[1][0], &Bs[0][0], 5, 1);          // t % 3 == 1
        if (t >= TPB) break;
        BODY(&Bs[2][0], &Bs[1][0], 5, 1);          // t % 3 == 2
        if (t >= TPB) break;
        BODY(&Bs[0][0], &Bs[2][0], 5, 1);          // t % 3 == 0
    }
    FLUSH_ROWS;

#undef ISSUE
#undef BODY
#undef ADV
#undef FLUSH_ROWS
#undef LOAD_AF
}

// Kernel 3: loss_i = ln2*(log2(T'_i) - s2'_i), mean over rows.
__global__ void __launch_bounds__(256) final_kernel(const float* __restrict__ Tg,
                                                    const float* __restrict__ Dg,
                                                    float* __restrict__ out) {
    __shared__ float red[4];
    const int i = blockIdx.x * 256 + threadIdx.x;
    float c = LN2F * (__log2f(Tg[i]) - Dg[i]) * (1.0f / (float)N_ROWS);
#pragma unroll
    for (int m = 1; m < 64; m <<= 1) c += __shfl_xor(c, m, 64);
    if ((threadIdx.x & 63) == 0) red[threadIdx.x >> 6] = c;
    __syncthreads();
    if (threadIdx.x == 0)
        atomicAdd(out, red[0] + red[1] + red[2] + red[3]);
}

extern "C" void kernel_launch(void* const* d_in, const int* in_sizes, int n_in,
                              void* d_out, int out_size, void* d_ws, size_t ws_size,
                              hipStream_t stream) {
    const float* emb = (const float*)d_in[0];
    float* out = (float*)d_out;
    bf16* Abf = (bf16*)d_ws;
    float* Tg = (float*)((char*)d_ws + WS_T_OFF);
    float* Dg = (float*)((char*)d_ws + WS_D_OFF);

    hipLaunchKernelGGL(normalize_kernel, dim3(N_ROWS / 4), dim3(256), 0, stream,
                       emb, Abf, Tg, Dg, out);
    hipLaunchKernelGGL(loss_kernel, dim3(NBLKS), dim3(256), 0, stream,
                       Abf, Tg);
    hipLaunchKernelGGL(final_kernel, dim3(N_ROWS / 256), dim3(256), 0, stream,
                       Tg, Dg, out);
}